// Round 3
// baseline (861.764 us; speedup 1.0000x reference)
//
#include <hip/hip_runtime.h>
#include <math.h>

// Problem constants (fixed by setup_inputs)
#define B_ 4
#define C_ 64
#define N_ 16384
#define K_ 16
#define H_ 8
#define CP 67            // C + 3 (xyz concat)
#define CPAD 68          // padded to 17 float4
#define NP 8             // points per block (256 thr = 8 p x 2 s x 16 k)
#define ESTRIDE 552      // e_lds row stride (8*68+8)
#define TSTRIDE 9        // out-transpose row stride (8 points + 1 pad)
#define WSZ (C_ * CPAD)  // 4352 floats per weight matrix, TRANSPOSED layout [j][o]

// Padded / pre-scaled weights, TRANSPOSED to [j][o] so weight reads coalesce
__device__ __align__(16) float wpad[3 * WSZ];

__global__ void setup_weights(const float* __restrict__ Wq,
                              const float* __restrict__ Wk,
                              const float* __restrict__ Wv) {
  int i = blockIdx.x * blockDim.x + threadIdx.x;
  if (i >= WSZ) return;
  int j = i >> 6, o = i & 63;          // wpad[j*64 + o] = W[o][j]
  float q = 0.f, kk = 0.f, v = 0.f;
  if (j < CP) {
    q = Wq[o * CP + j] * 0.35355339059327373f;  // fold 1/sqrt(D), D=8
    kk = Wk[o * CP + j];
    v = Wv[o * CP + j];
  }
  wpad[i] = q;
  wpad[WSZ + i] = kk;
  wpad[2 * WSZ + i] = v;
}

// ds_swizzle XOR within 32-lane half (BitMode: and=0x1F, or=0, xor=mask)
#define SWZ(v, imm) __int_as_float(__builtin_amdgcn_ds_swizzle(__float_as_int(v), (imm)))
#define XOR4 0x101F
#define XOR16 0x401F

// DPP lane exchange on the VALU pipe:
//   quad_perm 0xB1 = XOR1, 0x4E = XOR2; row_ror:8 = XOR8 within a 16-row;
//   row_ror:4 = rotate-4 (valid for all-reduce after quad stages).
#define DPP_XOR1 0xB1
#define DPP_XOR2 0x4E
#define DPP_ROR4 0x124
#define DPP_ROR8 0x128
template <int CTRL>
__device__ __forceinline__ float dppf(float x) {
  int i = __float_as_int(x);
  return __int_as_float(__builtin_amdgcn_update_dpp(i, i, CTRL, 0xF, 0xF, false));
}

// Pressure design: nbr[36] (half-tile) + ~45 working regs ~= 85 live.
// (256,4): VGPR cap 128 -> no squeeze-spill (rounds 1-2 regression mechanism).
__launch_bounds__(256, 4)
__global__ void pt_attn(const float* __restrict__ pcd,
                        const float* __restrict__ neighbors,
                        const float* __restrict__ xyz,
                        const int* __restrict__ idx_all,
                        float* __restrict__ out) {
  // x_lds: pcd_cat tile (8*68=544) reused as out-transpose (64*9=576)
  __shared__ __align__(16) float x_lds[640];
  __shared__ __align__(16) float e_lds[NP * ESTRIDE]; // per point: 8 heads x 68

  const int tid = threadIdx.x;
  const int k = tid & 15;          // neighbor index        (lane bits 0-3)
  const int s = (tid >> 4) & 1;    // channel-parity half   (lane bit 4)
  const int p = tid >> 5;          // point in tile 0..7    (lane bit 5 + wg)
  const int blk = blockIdx.x;
  const int b = blk >> 11;               // 2048 tiles per batch
  const int n0 = (blk & 2047) << 3;
  const int n = n0 + p;

  // ---- neighbor features: thread owns float4 groups j4 = 2t+s (t<8),
  //      plus j4=16 (xyz gather) on s==0. Coalesced: per inst a wave reads
  //      2 planes x 128B contiguous. ----
  float nbr[36];
  {
    const float* gp = neighbors + (size_t)b * (C_ * N_ * K_) +
                      (size_t)(n0 + p) * K_ + k + (size_t)s * 4 * (N_ * K_);
#pragma unroll
    for (int t = 0; t < 8; ++t)
#pragma unroll
      for (int u = 0; u < 4; ++u)
        nbr[4 * t + u] = gp[(size_t)(8 * t + u) * (N_ * K_)];
  }
  if (s == 0) {
    const int idx = idx_all[(b * N_ + n) * K_ + k];
    const float* gx = xyz + (size_t)b * (3 * N_) + idx;
    nbr[32] = gx[0];
    nbr[33] = gx[N_];
    nbr[34] = gx[2 * N_];
    nbr[35] = 0.f;  // pad (weights pad row is 0 too)
  }

  // ---- stage x = concat(pcd, xyz) for the 8 points ----
  {
    const int pp = tid & 7;
    const int cc = tid >> 3;  // 0..31
#pragma unroll
    for (int it = 0; it < 2; ++it) {
      int c = cc + 32 * it;
      x_lds[pp * CPAD + c] = pcd[((size_t)b * C_ + c) * N_ + n0 + pp];
    }
    if (tid < 24)
      x_lds[pp * CPAD + 64 + cc] = xyz[((size_t)b * 3 + cc) * N_ + n0 + pp];
    if (tid < 8)
      x_lds[tid * CPAD + 67] = 0.f;
  }
  __syncthreads();

  // ---- phase 1: q[4k..4k+3] of point p; j-parity partials combined via XOR16 ----
  float4 q4;
  {
    const float4* xr = (const float4*)(x_lds + p * CPAD);
    const float* wq = wpad + 4 * k;
    float ax = 0.f, ay = 0.f, az = 0.f, aw = 0.f;
#pragma unroll
    for (int t = 0; t < 8; ++t) {
      const int j4 = 2 * t + s;
      float4 xv = xr[j4];
#pragma unroll
      for (int jj = 0; jj < 4; ++jj) {
        float4 w = *(const float4*)(wq + (4 * j4 + jj) * 64);
        float xc = (jj == 0) ? xv.x : (jj == 1) ? xv.y : (jj == 2) ? xv.z : xv.w;
        ax += w.x * xc; ay += w.y * xc; az += w.z * xc; aw += w.w * xc;
      }
    }
    if (s == 0) {  // j4 = 16 (row 67 of wpad and x pad are both 0)
      float4 xv = xr[16];
#pragma unroll
      for (int jj = 0; jj < 4; ++jj) {
        float4 w = *(const float4*)(wq + (64 + jj) * 64);
        float xc = (jj == 0) ? xv.x : (jj == 1) ? xv.y : (jj == 2) ? xv.z : xv.w;
        ax += w.x * xc; ay += w.y * xc; az += w.z * xc; aw += w.w * xc;
      }
    }
    ax += SWZ(ax, XOR16);
    ay += SWZ(ay, XOR16);
    az += SWZ(az, XOR16);
    aw += SWZ(aw, XOR16);
    q4 = make_float4(ax, ay, az, aw);
  }

  // ---- phase 2: head h = k>>1; gather q[8h..8h+7] via quad XOR1 (k^1 holds
  //      the other 4 channels); each of the 4 workers (k&1, s) covers j4 =
  //      idx4 + 4t, idx4 = (k&1)*2+s; idx4==0 also does j4=16. ----
  {
    float bx = dppf<DPP_XOR1>(q4.x), by = dppf<DPP_XOR1>(q4.y);
    float bz = dppf<DPP_XOR1>(q4.z), bw = dppf<DPP_XOR1>(q4.w);
    const bool lo = (k & 1) == 0;
    const float qa0 = lo ? q4.x : bx, qa1 = lo ? q4.y : by;
    const float qa2 = lo ? q4.z : bz, qa3 = lo ? q4.w : bw;
    const float qa4 = lo ? bx : q4.x, qa5 = lo ? by : q4.y;
    const float qa6 = lo ? bz : q4.z, qa7 = lo ? bw : q4.w;
    const int h = k >> 1;
    const int idx4 = (k & 1) * 2 + s;
    const float* wk = wpad + WSZ + 8 * h;
    float4* er = (float4*)(e_lds + p * ESTRIDE + h * CPAD);
#pragma unroll
    for (int t = 0; t < 4; ++t) {
      const int j4 = idx4 + 4 * t;
      float r[4];
#pragma unroll
      for (int jj = 0; jj < 4; ++jj) {
        const float4 wl = *(const float4*)(wk + (4 * j4 + jj) * 64);
        const float4 wh = *(const float4*)(wk + (4 * j4 + jj) * 64 + 4);
        r[jj] = qa0 * wl.x + qa1 * wl.y + qa2 * wl.z + qa3 * wl.w +
                qa4 * wh.x + qa5 * wh.y + qa6 * wh.z + qa7 * wh.w;
      }
      er[j4] = make_float4(r[0], r[1], r[2], r[3]);
    }
    if (idx4 == 0) {
      float r[4];
#pragma unroll
      for (int jj = 0; jj < 4; ++jj) {
        const float4 wl = *(const float4*)(wk + (64 + jj) * 64);
        const float4 wh = *(const float4*)(wk + (64 + jj) * 64 + 4);
        r[jj] = qa0 * wl.x + qa1 * wl.y + qa2 * wl.z + qa3 * wl.w +
                qa4 * wh.x + qa5 * wh.y + qa6 * wh.z + qa7 * wh.w;
      }
      er[16] = make_float4(r[0], r[1], r[2], r[3]);
    }
  }
  // wave-local: e row p is produced and consumed by the same wave's lanes
  asm volatile("s_waitcnt lgkmcnt(0)" ::: "memory");
  __builtin_amdgcn_sched_barrier(0);

  // ---- phase 3: en[h] = e[h]·nb_k over own parity, + XOR16 partner; softmax
  //      over k via DPP within the 16-lane (p,s) row. ----
  float en[8];
#pragma unroll
  for (int hh = 0; hh < 8; ++hh) en[hh] = 0.f;
  {
    const float4* ep = (const float4*)(e_lds + p * ESTRIDE);
#pragma unroll
    for (int t = 0; t < 8; ++t) {
      const int j4 = 2 * t + s;
#pragma unroll
      for (int hh = 0; hh < 8; ++hh) {
        float4 e4 = ep[hh * 17 + j4];
        en[hh] += e4.x * nbr[4 * t + 0] + e4.y * nbr[4 * t + 1] +
                  e4.z * nbr[4 * t + 2] + e4.w * nbr[4 * t + 3];
      }
    }
    if (s == 0) {
#pragma unroll
      for (int hh = 0; hh < 8; ++hh) {
        float4 e4 = ep[hh * 17 + 16];
        en[hh] += e4.x * nbr[32] + e4.y * nbr[33] + e4.z * nbr[34] + e4.w * nbr[35];
      }
    }
  }
  float at[8];
#pragma unroll
  for (int hh = 0; hh < 8; ++hh) {
    float e0 = en[hh] + SWZ(en[hh], XOR16);  // combine channel-parity halves
    float m = e0;
    m = fmaxf(m, dppf<DPP_XOR1>(m));
    m = fmaxf(m, dppf<DPP_XOR2>(m));
    m = fmaxf(m, dppf<DPP_ROR4>(m));
    m = fmaxf(m, dppf<DPP_ROR8>(m));
    float e = __expf(e0 - m);
    float sum = e;
    sum += dppf<DPP_XOR1>(sum);
    sum += dppf<DPP_XOR2>(sum);
    sum += dppf<DPP_ROR4>(sum);
    sum += dppf<DPP_ROR8>(sum);
    at[hh] = e * __builtin_amdgcn_rcpf(sum);
  }

  // ---- permuted attn for the DPP reduce-scatter over k (lane bits 0-3):
  //      stages XOR8 (ror:8), XOR2 (quad), XOR1 (quad), XOR4 (ds_swizzle);
  //      lane k ends with head g = k.b3<<2|k.b1<<1|k.b0, dup over k.b2. ----
  const int g = (((k >> 3) & 1) << 2) | (((k >> 1) & 1) << 1) | (k & 1);
  float ap[8];
  {
    float t0[8], t1[8];
#pragma unroll
    for (int i = 0; i < 8; ++i) t0[i] = (k & 8) ? at[i ^ 4] : at[i];
#pragma unroll
    for (int i = 0; i < 8; ++i) t1[i] = (k & 2) ? t0[i ^ 2] : t0[i];
#pragma unroll
    for (int i = 0; i < 8; ++i) ap[i] = (k & 1) ? t1[i ^ 1] : t1[i];
  }

  // ---- phase 4: agg_h[j] over own parity groups; apply Wv cols ob..ob+3;
  //      then XOR16 combines the channel-parity partial outputs. ----
  const int ob = 8 * g + (k & 4);
  float xo0 = 0.f, xo1 = 0.f, xo2 = 0.f, xo3 = 0.f;
  const float* wv = wpad + 2 * WSZ + ob;

#define PH4_GROUP(M, ROWB)                                                   \
  {                                                                          \
    float agg0, agg1, agg2, agg3;                                            \
    _Pragma("unroll") for (int u = 0; u < 4; ++u) {                          \
      float nbj = nbr[4 * (M) + u];                                          \
      float s0 = ap[0] * nbj, s1 = ap[1] * nbj, s2 = ap[2] * nbj,            \
            s3 = ap[3] * nbj;                                                \
      float s4 = ap[4] * nbj, s5 = ap[5] * nbj, s6 = ap[6] * nbj,            \
            s7 = ap[7] * nbj;                                                \
      s0 += dppf<DPP_ROR8>(s4);                                              \
      s1 += dppf<DPP_ROR8>(s5);                                              \
      s2 += dppf<DPP_ROR8>(s6);                                              \
      s3 += dppf<DPP_ROR8>(s7);                                              \
      s0 += dppf<DPP_XOR2>(s2);                                              \
      s1 += dppf<DPP_XOR2>(s3);                                              \
      s0 += dppf<DPP_XOR1>(s1);                                              \
      s0 += SWZ(s0, XOR4);                                                   \
      if (u == 0) agg0 = s0;                                                 \
      else if (u == 1) agg1 = s0;                                            \
      else if (u == 2) agg2 = s0;                                            \
      else agg3 = s0;                                                        \
    }                                                                        \
    float4 w0 = *(const float4*)(wv + ((ROWB) + 0) * 64);                    \
    float4 w1 = *(const float4*)(wv + ((ROWB) + 1) * 64);                    \
    float4 w2 = *(const float4*)(wv + ((ROWB) + 2) * 64);                    \
    float4 w3 = *(const float4*)(wv + ((ROWB) + 3) * 64);                    \
    xo0 += w0.x * agg0 + w1.x * agg1 + w2.x * agg2 + w3.x * agg3;            \
    xo1 += w0.y * agg0 + w1.y * agg1 + w2.y * agg2 + w3.y * agg3;            \
    xo2 += w0.z * agg0 + w1.z * agg1 + w2.z * agg2 + w3.z * agg3;            \
    xo3 += w0.w * agg0 + w1.w * agg1 + w2.w * agg2 + w3.w * agg3;            \
  }

#pragma unroll
  for (int t = 0; t < 8; ++t) {
    PH4_GROUP(t, 4 * (2 * t + s));
  }
  if (s == 0) {  // j4 = 16 (exec mask covers whole 16-lane rows: DPP-safe)
    PH4_GROUP(8, 64);
  }
  xo0 += SWZ(xo0, XOR16);
  xo1 += SWZ(xo1, XOR16);
  xo2 += SWZ(xo2, XOR16);
  xo3 += SWZ(xo3, XOR16);

  // ---- store: transpose through freed x_lds (64 x TSTRIDE), each thread
  //      writes its 2 channels, then one coalesced float2 per thread out. ----
  __syncthreads();  // all waves done reading x_lds (phase 1)
  {
    const int oo = ob + 2 * s;
    x_lds[(oo + 0) * TSTRIDE + p] = s ? xo2 : xo0;
    x_lds[(oo + 1) * TSTRIDE + p] = s ? xo3 : xo1;
  }
  __syncthreads();
  {
    const int o = tid >> 2;          // 0..63
    const int pc = (tid & 3) << 1;   // 0,2,4,6
    const float* ol = x_lds + o * TSTRIDE + pc;
    *(float2*)(out + ((size_t)b * C_ + o) * N_ + n0 + pc) = make_float2(ol[0], ol[1]);
  }
}

extern "C" void kernel_launch(void* const* d_in, const int* in_sizes, int n_in,
                              void* d_out, int out_size, void* d_ws, size_t ws_size,
                              hipStream_t stream) {
  const float* pcd = (const float*)d_in[0];
  const float* neighbors = (const float*)d_in[1];
  const float* xyz = (const float*)d_in[2];
  const float* Wq = (const float*)d_in[3];
  const float* Wk = (const float*)d_in[4];
  const float* Wv = (const float*)d_in[5];
  const int* idx = (const int*)d_in[6];
  float* out = (float*)d_out;

  setup_weights<<<(WSZ + 255) / 256, 256, 0, stream>>>(Wq, Wk, Wv);
  pt_attn<<<B_ * (N_ / NP), 256, 0, stream>>>(pcd, neighbors, xyz, idx, out);
}

// Round 5
// 577.468 us; speedup vs baseline: 1.4923x; 1.4923x over previous
//
#include <hip/hip_runtime.h>
#include <math.h>

// Problem constants (fixed by setup_inputs)
#define B_ 4
#define C_ 64
#define N_ 16384
#define K_ 16
#define H_ 8
#define CP 67            // C + 3 (xyz concat)
#define CPAD 68          // padded to 17 float4
#define NP 8             // points per block (256 thr = 8 p x 2 s x 16 k)
#define ESTRIDE 552      // e_lds row stride (8*68+8)
#define TSTRIDE 9        // out-transpose row stride (8 points + 1 pad)
#define WSZ (C_ * CPAD)  // 4352 floats per weight matrix, TRANSPOSED layout [j][o]

// Padded / pre-scaled weights, TRANSPOSED to [j][o] so weight reads coalesce
__device__ __align__(16) float wpad[3 * WSZ];

__global__ void setup_weights(const float* __restrict__ Wq,
                              const float* __restrict__ Wk,
                              const float* __restrict__ Wv) {
  int i = blockIdx.x * blockDim.x + threadIdx.x;
  if (i >= WSZ) return;
  int j = i >> 6, o = i & 63;          // wpad[j*64 + o] = W[o][j]
  float q = 0.f, kk = 0.f, v = 0.f;
  if (j < CP) {
    q = Wq[o * CP + j] * 0.35355339059327373f;  // fold 1/sqrt(D), D=8
    kk = Wk[o * CP + j];
    v = Wv[o * CP + j];
  }
  wpad[i] = q;
  wpad[WSZ + i] = kk;
  wpad[2 * WSZ + i] = v;
}

// ds_swizzle XOR within 32-lane half (BitMode: and=0x1F, or=0, xor=mask)
#define SWZ(v, imm) __int_as_float(__builtin_amdgcn_ds_swizzle(__float_as_int(v), (imm)))
#define XOR4 0x101F
#define XOR16 0x401F

// DPP lane exchange on the VALU pipe:
//   quad_perm 0xB1 = XOR1, 0x4E = XOR2; row_ror:8 = XOR8 within a 16-row;
//   row_ror:4 = rotate-4 (valid for all-reduce after quad stages).
#define DPP_XOR1 0xB1
#define DPP_XOR2 0x4E
#define DPP_ROR4 0x124
#define DPP_ROR8 0x128
template <int CTRL>
__device__ __forceinline__ float dppf(float x) {
  int i = __float_as_int(x);
  return __int_as_float(__builtin_amdgcn_update_dpp(i, i, CTRL, 0xF, 0xF, false));
}

// VGPR-cap calibration on THIS toolchain (measured via rocprof VGPR_Count):
//   __launch_bounds__(256,3) -> 84 regs (~256/3), (256,4) -> 64 (=256/4).
// i.e. cap ~= 256 / second-arg, NOT 512/waves-per-EU. Natural live set here
// is ~85-95 (nbr[36] half-tile + working regs), so (256,2) -> 128-reg cap:
// zero spill (rounds 1-3 all lost to scratch traffic from squeeze-spill).
__launch_bounds__(256, 2)
__global__ void pt_attn(const float* __restrict__ pcd,
                        const float* __restrict__ neighbors,
                        const float* __restrict__ xyz,
                        const int* __restrict__ idx_all,
                        float* __restrict__ out) {
  // x_lds: pcd_cat tile (8*68=544) reused as out-transpose (64*9=576)
  __shared__ __align__(16) float x_lds[640];
  __shared__ __align__(16) float e_lds[NP * ESTRIDE]; // per point: 8 heads x 68

  const int tid = threadIdx.x;
  const int k = tid & 15;          // neighbor index        (lane bits 0-3)
  const int s = (tid >> 4) & 1;    // channel-parity half   (lane bit 4)
  const int p = tid >> 5;          // point in tile 0..7    (lane bit 5 + wg)
  const int blk = blockIdx.x;
  const int b = blk >> 11;               // 2048 tiles per batch
  const int n0 = (blk & 2047) << 3;
  const int n = n0 + p;

  // ---- neighbor features: thread owns float4 groups j4 = 2t+s (t<8),
  //      plus j4=16 (xyz gather) on s==0. Coalesced: per inst a wave reads
  //      2 planes x 128B contiguous. ----
  float nbr[36];
  {
    const float* gp = neighbors + (size_t)b * (C_ * N_ * K_) +
                      (size_t)(n0 + p) * K_ + k + (size_t)s * 4 * (N_ * K_);
#pragma unroll
    for (int t = 0; t < 8; ++t)
#pragma unroll
      for (int u = 0; u < 4; ++u)
        nbr[4 * t + u] = gp[(size_t)(8 * t + u) * (N_ * K_)];
  }
  if (s == 0) {
    const int idx = idx_all[(b * N_ + n) * K_ + k];
    const float* gx = xyz + (size_t)b * (3 * N_) + idx;
    nbr[32] = gx[0];
    nbr[33] = gx[N_];
    nbr[34] = gx[2 * N_];
    nbr[35] = 0.f;  // pad (weights pad row is 0 too)
  }

  // ---- stage x = concat(pcd, xyz) for the 8 points ----
  {
    const int pp = tid & 7;
    const int cc = tid >> 3;  // 0..31
#pragma unroll
    for (int it = 0; it < 2; ++it) {
      int c = cc + 32 * it;
      x_lds[pp * CPAD + c] = pcd[((size_t)b * C_ + c) * N_ + n0 + pp];
    }
    if (tid < 24)
      x_lds[pp * CPAD + 64 + cc] = xyz[((size_t)b * 3 + cc) * N_ + n0 + pp];
    if (tid < 8)
      x_lds[tid * CPAD + 67] = 0.f;
  }
  __syncthreads();

  // ---- phase 1: q[4k..4k+3] of point p; j-parity partials combined via XOR16 ----
  float4 q4;
  {
    const float4* xr = (const float4*)(x_lds + p * CPAD);
    const float* wq = wpad + 4 * k;
    float ax = 0.f, ay = 0.f, az = 0.f, aw = 0.f;
#pragma unroll
    for (int t = 0; t < 8; ++t) {
      const int j4 = 2 * t + s;
      float4 xv = xr[j4];
#pragma unroll
      for (int jj = 0; jj < 4; ++jj) {
        float4 w = *(const float4*)(wq + (4 * j4 + jj) * 64);
        float xc = (jj == 0) ? xv.x : (jj == 1) ? xv.y : (jj == 2) ? xv.z : xv.w;
        ax += w.x * xc; ay += w.y * xc; az += w.z * xc; aw += w.w * xc;
      }
    }
    if (s == 0) {  // j4 = 16 (row 67 of wpad and x pad are both 0)
      float4 xv = xr[16];
#pragma unroll
      for (int jj = 0; jj < 4; ++jj) {
        float4 w = *(const float4*)(wq + (64 + jj) * 64);
        float xc = (jj == 0) ? xv.x : (jj == 1) ? xv.y : (jj == 2) ? xv.z : xv.w;
        ax += w.x * xc; ay += w.y * xc; az += w.z * xc; aw += w.w * xc;
      }
    }
    ax += SWZ(ax, XOR16);
    ay += SWZ(ay, XOR16);
    az += SWZ(az, XOR16);
    aw += SWZ(aw, XOR16);
    q4 = make_float4(ax, ay, az, aw);
  }

  // ---- phase 2: head h = k>>1; gather q[8h..8h+7] via quad XOR1 (k^1 holds
  //      the other 4 channels); each of the 4 workers (k&1, s) covers j4 =
  //      idx4 + 4t, idx4 = (k&1)*2+s; idx4==0 also does j4=16. ----
  {
    float bx = dppf<DPP_XOR1>(q4.x), by = dppf<DPP_XOR1>(q4.y);
    float bz = dppf<DPP_XOR1>(q4.z), bw = dppf<DPP_XOR1>(q4.w);
    const bool lo = (k & 1) == 0;
    const float qa0 = lo ? q4.x : bx, qa1 = lo ? q4.y : by;
    const float qa2 = lo ? q4.z : bz, qa3 = lo ? q4.w : bw;
    const float qa4 = lo ? bx : q4.x, qa5 = lo ? by : q4.y;
    const float qa6 = lo ? bz : q4.z, qa7 = lo ? bw : q4.w;
    const int h = k >> 1;
    const int idx4 = (k & 1) * 2 + s;
    const float* wk = wpad + WSZ + 8 * h;
    float4* er = (float4*)(e_lds + p * ESTRIDE + h * CPAD);
#pragma unroll
    for (int t = 0; t < 4; ++t) {
      const int j4 = idx4 + 4 * t;
      float r[4];
#pragma unroll
      for (int jj = 0; jj < 4; ++jj) {
        const float4 wl = *(const float4*)(wk + (4 * j4 + jj) * 64);
        const float4 wh = *(const float4*)(wk + (4 * j4 + jj) * 64 + 4);
        r[jj] = qa0 * wl.x + qa1 * wl.y + qa2 * wl.z + qa3 * wl.w +
                qa4 * wh.x + qa5 * wh.y + qa6 * wh.z + qa7 * wh.w;
      }
      er[j4] = make_float4(r[0], r[1], r[2], r[3]);
    }
    if (idx4 == 0) {
      float r[4];
#pragma unroll
      for (int jj = 0; jj < 4; ++jj) {
        const float4 wl = *(const float4*)(wk + (64 + jj) * 64);
        const float4 wh = *(const float4*)(wk + (64 + jj) * 64 + 4);
        r[jj] = qa0 * wl.x + qa1 * wl.y + qa2 * wl.z + qa3 * wl.w +
                qa4 * wh.x + qa5 * wh.y + qa6 * wh.z + qa7 * wh.w;
      }
      er[16] = make_float4(r[0], r[1], r[2], r[3]);
    }
  }
  // wave-local: e row p is produced and consumed by the same wave's lanes
  asm volatile("s_waitcnt lgkmcnt(0)" ::: "memory");
  __builtin_amdgcn_sched_barrier(0);

  // ---- phase 3: en[h] = e[h]·nb_k over own parity, + XOR16 partner; softmax
  //      over k via DPP within the 16-lane (p,s) row. ----
  float en[8];
#pragma unroll
  for (int hh = 0; hh < 8; ++hh) en[hh] = 0.f;
  {
    const float4* ep = (const float4*)(e_lds + p * ESTRIDE);
#pragma unroll
    for (int t = 0; t < 8; ++t) {
      const int j4 = 2 * t + s;
#pragma unroll
      for (int hh = 0; hh < 8; ++hh) {
        float4 e4 = ep[hh * 17 + j4];
        en[hh] += e4.x * nbr[4 * t + 0] + e4.y * nbr[4 * t + 1] +
                  e4.z * nbr[4 * t + 2] + e4.w * nbr[4 * t + 3];
      }
    }
    if (s == 0) {
#pragma unroll
      for (int hh = 0; hh < 8; ++hh) {
        float4 e4 = ep[hh * 17 + 16];
        en[hh] += e4.x * nbr[32] + e4.y * nbr[33] + e4.z * nbr[34] + e4.w * nbr[35];
      }
    }
  }
  float at[8];
#pragma unroll
  for (int hh = 0; hh < 8; ++hh) {
    float e0 = en[hh] + SWZ(en[hh], XOR16);  // combine channel-parity halves
    float m = e0;
    m = fmaxf(m, dppf<DPP_XOR1>(m));
    m = fmaxf(m, dppf<DPP_XOR2>(m));
    m = fmaxf(m, dppf<DPP_ROR4>(m));
    m = fmaxf(m, dppf<DPP_ROR8>(m));
    float e = __expf(e0 - m);
    float sum = e;
    sum += dppf<DPP_XOR1>(sum);
    sum += dppf<DPP_XOR2>(sum);
    sum += dppf<DPP_ROR4>(sum);
    sum += dppf<DPP_ROR8>(sum);
    at[hh] = e * __builtin_amdgcn_rcpf(sum);
  }

  // ---- permuted attn for the DPP reduce-scatter over k (lane bits 0-3):
  //      stages XOR8 (ror:8), XOR2 (quad), XOR1 (quad), XOR4 (ds_swizzle);
  //      lane k ends with head g = k.b3<<2|k.b1<<1|k.b0, dup over k.b2. ----
  const int g = (((k >> 3) & 1) << 2) | (((k >> 1) & 1) << 1) | (k & 1);
  float ap[8];
  {
    float t0[8], t1[8];
#pragma unroll
    for (int i = 0; i < 8; ++i) t0[i] = (k & 8) ? at[i ^ 4] : at[i];
#pragma unroll
    for (int i = 0; i < 8; ++i) t1[i] = (k & 2) ? t0[i ^ 2] : t0[i];
#pragma unroll
    for (int i = 0; i < 8; ++i) ap[i] = (k & 1) ? t1[i ^ 1] : t1[i];
  }

  // ---- phase 4: agg_h[j] over own parity groups; apply Wv cols ob..ob+3;
  //      then XOR16 combines the channel-parity partial outputs. ----
  const int ob = 8 * g + (k & 4);
  float xo0 = 0.f, xo1 = 0.f, xo2 = 0.f, xo3 = 0.f;
  const float* wv = wpad + 2 * WSZ + ob;

#define PH4_GROUP(M, ROWB)                                                   \
  {                                                                          \
    float agg0, agg1, agg2, agg3;                                            \
    _Pragma("unroll") for (int u = 0; u < 4; ++u) {                          \
      float nbj = nbr[4 * (M) + u];                                          \
      float s0 = ap[0] * nbj, s1 = ap[1] * nbj, s2 = ap[2] * nbj,            \
            s3 = ap[3] * nbj;                                                \
      float s4 = ap[4] * nbj, s5 = ap[5] * nbj, s6 = ap[6] * nbj,            \
            s7 = ap[7] * nbj;                                                \
      s0 += dppf<DPP_ROR8>(s4);                                              \
      s1 += dppf<DPP_ROR8>(s5);                                              \
      s2 += dppf<DPP_ROR8>(s6);                                              \
      s3 += dppf<DPP_ROR8>(s7);                                              \
      s0 += dppf<DPP_XOR2>(s2);                                              \
      s1 += dppf<DPP_XOR2>(s3);                                              \
      s0 += dppf<DPP_XOR1>(s1);                                              \
      s0 += SWZ(s0, XOR4);                                                   \
      if (u == 0) agg0 = s0;                                                 \
      else if (u == 1) agg1 = s0;                                            \
      else if (u == 2) agg2 = s0;                                            \
      else agg3 = s0;                                                        \
    }                                                                        \
    float4 w0 = *(const float4*)(wv + ((ROWB) + 0) * 64);                    \
    float4 w1 = *(const float4*)(wv + ((ROWB) + 1) * 64);                    \
    float4 w2 = *(const float4*)(wv + ((ROWB) + 2) * 64);                    \
    float4 w3 = *(const float4*)(wv + ((ROWB) + 3) * 64);                    \
    xo0 += w0.x * agg0 + w1.x * agg1 + w2.x * agg2 + w3.x * agg3;            \
    xo1 += w0.y * agg0 + w1.y * agg1 + w2.y * agg2 + w3.y * agg3;            \
    xo2 += w0.z * agg0 + w1.z * agg1 + w2.z * agg2 + w3.z * agg3;            \
    xo3 += w0.w * agg0 + w1.w * agg1 + w2.w * agg2 + w3.w * agg3;            \
  }

#pragma unroll
  for (int t = 0; t < 8; ++t) {
    PH4_GROUP(t, 4 * (2 * t + s));
  }
  if (s == 0) {  // j4 = 16 (exec mask covers whole 16-lane rows: DPP-safe)
    PH4_GROUP(8, 64);
  }
  xo0 += SWZ(xo0, XOR16);
  xo1 += SWZ(xo1, XOR16);
  xo2 += SWZ(xo2, XOR16);
  xo3 += SWZ(xo3, XOR16);

  // ---- store: transpose through freed x_lds (64 x TSTRIDE), each thread
  //      writes its 2 channels, then one coalesced float2 per thread out. ----
  __syncthreads();  // all waves done reading x_lds (phase 1)
  {
    const int oo = ob + 2 * s;
    x_lds[(oo + 0) * TSTRIDE + p] = s ? xo2 : xo0;
    x_lds[(oo + 1) * TSTRIDE + p] = s ? xo3 : xo1;
  }
  __syncthreads();
  {
    const int o = tid >> 2;          // 0..63
    const int pc = (tid & 3) << 1;   // 0,2,4,6
    const float* ol = x_lds + o * TSTRIDE + pc;
    *(float2*)(out + ((size_t)b * C_ + o) * N_ + n0 + pc) = make_float2(ol[0], ol[1]);
  }
}

extern "C" void kernel_launch(void* const* d_in, const int* in_sizes, int n_in,
                              void* d_out, int out_size, void* d_ws, size_t ws_size,
                              hipStream_t stream) {
  const float* pcd = (const float*)d_in[0];
  const float* neighbors = (const float*)d_in[1];
  const float* xyz = (const float*)d_in[2];
  const float* Wq = (const float*)d_in[3];
  const float* Wk = (const float*)d_in[4];
  const float* Wv = (const float*)d_in[5];
  const int* idx = (const int*)d_in[6];
  float* out = (float*)d_out;

  setup_weights<<<(WSZ + 255) / 256, 256, 0, stream>>>(Wq, Wk, Wv);
  pt_attn<<<B_ * (N_ / NP), 256, 0, stream>>>(pcd, neighbors, xyz, idx, out);
}